// Round 1
// 1310.333 us; speedup vs baseline: 1.1863x; 1.1863x over previous
//
#include <hip/hip_runtime.h>

#define N_NODES 100000
#define M_HYPER 50000
#define N_TOTAL 150000
#define D_IN    512
#define H_LAT   256
#define N_CLASS 40
#define NNZ_E   4800000
#define CNT_PAD 151552   // 37 * 4096, >= N_TOTAL+1
#define BK      128
#define BROWS   256
#define NB      ((N_TOTAL + BROWS - 1) / BROWS)   // 586 buckets
#define CH      4096

// layer scales: emb8 = 16*emb; each spmm stores 8*a (a already carries input scale)
// => c1_8 = 128*c1, c2_8 = 1024*c2, c3_8 = 8192*c3
#define S_EMB   16.0f
#define SP_OUT  8.0f
#define INV1    (1.0f / 128.0f)
#define INV2    (1.0f / 1024.0f)
#define INV3    (1.0f / 8192.0f)

typedef float  floatx4 __attribute__((ext_vector_type(4)));
typedef float  floatx2 __attribute__((ext_vector_type(2)));
typedef __bf16 bf16x8  __attribute__((ext_vector_type(8)));

__device__ __forceinline__ unsigned short bf16_rne(float f) {
    unsigned u = __float_as_uint(f);
    return (unsigned short)((u + 0x7FFFu + ((u >> 16) & 1u)) >> 16);
}
__device__ __forceinline__ float blo(unsigned w) { return __uint_as_float(w << 16); }
__device__ __forceinline__ float bhi(unsigned w) { return __uint_as_float(w & 0xFFFF0000u); }

__device__ __forceinline__ unsigned pack4fp8(float f0, float f1, float f2, float f3) {
    int d = __builtin_amdgcn_cvt_pk_fp8_f32(f0, f1, 0, false);
    d = __builtin_amdgcn_cvt_pk_fp8_f32(f2, f3, d, true);
    return (unsigned)d;
}

// ---------------- W_red transpose + bf16 convert: W[512][256] -> WT[256][512] ----------------
__global__ void __launch_bounds__(256) prep_wt_kernel(const float* __restrict__ W,
                                                      unsigned short* __restrict__ WT) {
    int t = blockIdx.x * 256 + threadIdx.x;
    if (t < D_IN * H_LAT) {
        int k = t >> 8;
        int n = t & 255;
        WT[n * D_IN + k] = bf16_rne(W[t]);
    }
}

// ---------------- GEMM1: emb = X @ W_red + b_red  (LDS-tiled bf16 MFMA) ----------------------
__global__ void __launch_bounds__(256, 3) gemm1_kernel(const float* __restrict__ X,
                                                       const unsigned short* __restrict__ WT,
                                                       const float* __restrict__ brd,
                                                       unsigned short* __restrict__ emb,
                                                       unsigned char* __restrict__ emb8) {
    __shared__ __align__(16) unsigned short smem[64 * (H_LAT + 8)];   // 33.8 KB
    unsigned short (*As)[BK + 8]    = (unsigned short (*)[BK + 8])smem;
    unsigned short (*Cs)[H_LAT + 8] = (unsigned short (*)[H_LAT + 8])smem;

    int tid  = threadIdx.x;
    int wv   = tid >> 6;
    int lane = tid & 63;
    int l16  = lane & 15;
    int quad = lane >> 4;
    int row0 = blockIdx.x * 64;

    int cst = (tid & 31) << 2;   // staging col (float idx), fixed per thread
    int rst = tid >> 5;          // staging row base 0..7
    const float* xbase = X + cst;

    float4 pf[8];
#pragma unroll
    for (int j = 0; j < 8; ++j) {
        int gr = min(row0 + rst + 8 * j, N_TOTAL - 1);
        pf[j] = *(const float4*)(xbase + (size_t)gr * D_IN);
    }

    floatx4 acc[4][4];
#pragma unroll
    for (int a = 0; a < 4; ++a)
#pragma unroll
        for (int b = 0; b < 4; ++b) acc[a][b] = (floatx4)0.f;

#pragma unroll 1
    for (int k0 = 0; k0 < D_IN; k0 += BK) {
        // regs (chunk k0) -> LDS as bf16
#pragma unroll
        for (int j = 0; j < 8; ++j) {
            ushort4 u;
            u.x = bf16_rne(pf[j].x); u.y = bf16_rne(pf[j].y);
            u.z = bf16_rne(pf[j].z); u.w = bf16_rne(pf[j].w);
            *(ushort4*)(&As[rst + 8 * j][cst]) = u;
        }
        __syncthreads();
        // issue next chunk's global loads now; they land during the MFMA phase below
        if (k0 + BK < D_IN) {
#pragma unroll
            for (int j = 0; j < 8; ++j) {
                int gr = min(row0 + rst + 8 * j, N_TOTAL - 1);
                pf[j] = *(const float4*)(xbase + (size_t)gr * D_IN + k0 + BK);
            }
        }
#pragma unroll
        for (int ks = 0; ks < BK; ks += 32) {
            bf16x8 af[4];
#pragma unroll
            for (int rt = 0; rt < 4; ++rt)
                af[rt] = *(const bf16x8*)(&As[rt * 16 + l16][ks + quad * 8]);
#pragma unroll
            for (int ct = 0; ct < 4; ++ct) {
                int col = wv * 64 + ct * 16 + l16;
                bf16x8 bw = *(const bf16x8*)(WT + (size_t)col * D_IN + k0 + ks + quad * 8);
#pragma unroll
                for (int rt = 0; rt < 4; ++rt)
                    acc[rt][ct] = __builtin_amdgcn_mfma_f32_16x16x32_bf16(af[rt], bw, acc[rt][ct], 0, 0, 0);
            }
        }
        __syncthreads();
    }

    // acc (+bias) -> LDS row-major
#pragma unroll
    for (int ct = 0; ct < 4; ++ct) {
        int col = wv * 64 + ct * 16 + l16;
        float bias = brd[col];
#pragma unroll
        for (int rt = 0; rt < 4; ++rt)
#pragma unroll
            for (int r = 0; r < 4; ++r)
                Cs[rt * 16 + quad * 4 + r][col] = bf16_rne(acc[rt][ct][r] + bias);
    }
    __syncthreads();

    // bf16 store, coalesced uint4, only rows < N_NODES
    int nbf = N_NODES - row0;
#pragma unroll
    for (int j = 0; j < 8; ++j) {
        int idx = tid + 256 * j;
        int r = idx >> 5;
        int cq = (idx & 31) * 8;
        if (r < nbf)
            *(uint4*)(emb + (size_t)(row0 + r) * H_LAT + cq) = *(const uint4*)(&Cs[r][cq]);
    }
    // fp8 store, coalesced uint4, all valid rows
#pragma unroll
    for (int j = 0; j < 4; ++j) {
        int idx = tid + 256 * j;
        int r = idx >> 4;
        int cq = (idx & 15) * 16;
        if (row0 + r < N_TOTAL) {
            const unsigned short* s = &Cs[r][cq];
            uint4 w0 = *(const uint4*)s;
            uint4 w1 = *(const uint4*)(s + 8);
            uint4 o;
            o.x = pack4fp8(S_EMB * blo(w0.x), S_EMB * bhi(w0.x), S_EMB * blo(w0.y), S_EMB * bhi(w0.y));
            o.y = pack4fp8(S_EMB * blo(w0.z), S_EMB * bhi(w0.z), S_EMB * blo(w0.w), S_EMB * bhi(w0.w));
            o.z = pack4fp8(S_EMB * blo(w1.x), S_EMB * bhi(w1.x), S_EMB * blo(w1.y), S_EMB * bhi(w1.y));
            o.w = pack4fp8(S_EMB * blo(w1.z), S_EMB * bhi(w1.z), S_EMB * blo(w1.w), S_EMB * bhi(w1.w));
            *(uint4*)(emb8 + (size_t)(row0 + r) * H_LAT + cq) = o;
        }
    }
}

// ---------------- coarse bucket counts (586 bins, LDS-aggregated) ----------------
// Replaces the per-row global-atomic histogram (was ~190 us: 4.8M device-scope
// atomics -> 32B fabric transactions each). Global atomic count: 4.8M -> ~600K.
__global__ void __launch_bounds__(256) bcnt_kernel(const int* __restrict__ rows,
                                                   int* __restrict__ bcnt) {
    __shared__ int h[NB];
    int tid = threadIdx.x;
    for (int i = tid; i < NB; i += 256) h[i] = 0;
    __syncthreads();
    long base = (long)blockIdx.x * (CH / 4);
    const int4* r4 = (const int4*)rows;
#pragma unroll
    for (int j = 0; j < 4; ++j) {
        long e = base + j * 256 + tid;
        if (e < NNZ_E / 4) {
            int4 r = r4[e];
            atomicAdd(&h[r.x >> 8], 1);
            atomicAdd(&h[r.y >> 8], 1);
            atomicAdd(&h[r.z >> 8], 1);
            atomicAdd(&h[r.w >> 8], 1);
        }
    }
    __syncthreads();
    for (int i = tid; i < NB; i += 256) {
        int c = h[i];
        if (c) atomicAdd(&bcnt[i], c);
    }
}

// ---------------- bucket scan: 586 values, one block ----------------
// Replaces the 151552-element single-block scan + initfill.
__global__ void __launch_bounds__(1024) bscan_kernel(const int* __restrict__ bcnt,
                                                     int* __restrict__ bptr,
                                                     int* __restrict__ bucket_fill) {
    __shared__ int ws[16];
    int tid = threadIdx.x;
    int lane = tid & 63, wid = tid >> 6;
    int v = (tid < NB) ? bcnt[tid] : 0;
    int s = v;
#pragma unroll
    for (int d = 1; d < 64; d <<= 1) {
        int o = __shfl_up(s, d);
        if (lane >= d) s += o;
    }
    if (lane == 63) ws[wid] = s;
    __syncthreads();
    if (wid == 0) {
        int w = (lane < 16) ? ws[lane] : 0;
#pragma unroll
        for (int d = 1; d < 16; d <<= 1) {
            int o = __shfl_up(w, d);
            if (lane >= d) w += o;
        }
        if (lane < 16) ws[lane] = w;
    }
    __syncthreads();
    int excl = s - v + ((wid > 0) ? ws[wid - 1] : 0);
    if (tid < NB) {
        bptr[tid] = excl;
        bucket_fill[tid] = excl;
    }
    if (tid == 0) bptr[NB] = NNZ_E;
}

// Phase A: bin edges into 586 coarse buckets (contiguous runs per block-bin -> compact writes)
__global__ void __launch_bounds__(256) binA_kernel(const int* __restrict__ rows,
                                                   const int* __restrict__ cols,
                                                   const float* __restrict__ vals,
                                                   int* __restrict__ bucket_fill,
                                                   int2* __restrict__ binned) {
    __shared__ int hist[NB];
    int tid = threadIdx.x;
    long base = (long)blockIdx.x * CH;
    for (int i = tid; i < NB; i += 256) hist[i] = 0;
    __syncthreads();

    int mybkt[16];
    int myrl[16];
#pragma unroll
    for (int j = 0; j < 16; ++j) {
        long e = base + j * 256 + tid;
        int b = -1, rl = 0;
        if (e < NNZ_E) {
            int r = rows[e];
            b = r >> 8;
            rl = r & 255;
            atomicAdd(&hist[b], 1);
        }
        mybkt[j] = b; myrl[j] = rl;
    }
    __syncthreads();
    for (int b = tid; b < NB; b += 256) {
        int c = hist[b];
        int g = 0;
        if (c > 0) g = atomicAdd(&bucket_fill[b], c);
        hist[b] = g;
    }
    __syncthreads();
#pragma unroll
    for (int j = 0; j < 16; ++j) {
        long e = base + j * 256 + tid;
        if (e < NNZ_E) {
            int b = mybkt[j];
            int pos = atomicAdd(&hist[b], 1);
            int c = cols[e];
            float v = vals[e];
            binned[pos] = make_int2(c | (myrl[j] << 18), __float_as_int(v));
        }
    }
}

// Phase B: one bucket per block. LDS 256-bin histogram + LDS scan -> writes row_ptr for
// its 256 rows, then scatters edges to csr_ev with LDS-atomic offsets.
// Replaces 4.8M global row_ofs atomics with LDS atomics; second binned read is L2-hot.
__global__ void __launch_bounds__(256) binB_kernel(const int* __restrict__ bptr,
                                                   const int2* __restrict__ binned,
                                                   int* __restrict__ row_ptr,
                                                   int2* __restrict__ csr_ev) {
    __shared__ int lh[256];
    __shared__ int lofs[256];
    __shared__ int wsum[4];
    int b = blockIdx.x;
    int tid = threadIdx.x;
    int s = bptr[b], e = bptr[b + 1];

    lh[tid] = 0;
    __syncthreads();
    for (int t = s + tid; t < e; t += 256)
        atomicAdd(&lh[((unsigned)binned[t].x) >> 18], 1);
    __syncthreads();

    // 256-bin exclusive scan
    int v = lh[tid];
    int lane = tid & 63, wid = tid >> 6;
    int sc = v;
#pragma unroll
    for (int d = 1; d < 64; d <<= 1) {
        int o = __shfl_up(sc, d);
        if (lane >= d) sc += o;
    }
    if (lane == 63) wsum[wid] = sc;
    __syncthreads();
    int woff = 0;
    if (wid > 0) woff = wsum[0];
    if (wid > 1) woff += wsum[1];
    if (wid > 2) woff += wsum[2];
    int excl = sc - v + woff;
    lofs[tid] = s + excl;
    row_ptr[b * BROWS + tid] = s + excl;   // last bucket naturally yields row_ptr[N_TOTAL]=NNZ
    __syncthreads();

    for (int t = s + tid; t < e; t += 256) {
        int2 w = binned[t];
        int rl  = ((unsigned)w.x) >> 18;
        int col = w.x & 0x3FFFF;
        int p = atomicAdd(&lofs[rl], 1);
        csr_ev[p] = make_int2(col, w.y);
    }
}

// ---------------- SpMM (fp8): cout8[r,:] = SP_OUT * sum_e val[e] * cin8[col[e],:] --------------
__global__ void __launch_bounds__(256) spmm8_kernel(const unsigned char* __restrict__ cin8,
                                                    unsigned char* __restrict__ cout8,
                                                    const int* __restrict__ row_ptr,
                                                    const int2* __restrict__ csr_ev,
                                                    int nrows) {
    int r = (blockIdx.x * 256 + threadIdx.x) >> 6;
    if (r >= nrows) return;
    int lane = threadIdx.x & 63;
    int q   = lane >> 4;
    int l16 = lane & 15;
    int beg = row_ptr[r], end = row_ptr[r + 1];

    float a[16];
#pragma unroll
    for (int j = 0; j < 16; ++j) a[j] = 0.f;
    const unsigned char* basep = cin8 + l16 * 16;

    for (int b = beg; b < end; b += 64) {
        int e = b + lane;
        int2 ev = (e < end) ? csr_ev[e] : make_int2(0, 0);  // col 0 / val 0 -> harmless
        int n = min(64, end - b);
        for (int i = 0; i < n; i += 16) {
            int cc[4]; float vv[4]; uint4 g[4];
#pragma unroll
            for (int u = 0; u < 4; ++u) {
                int src = i + 4 * u + q;
                cc[u] = __shfl(ev.x, src);
                vv[u] = __uint_as_float((unsigned)__shfl(ev.y, src));
            }
#pragma unroll
            for (int u = 0; u < 4; ++u) {
                if (i + 4 * u < n) g[u] = *(const uint4*)(basep + (size_t)cc[u] * H_LAT);
                else               g[u] = make_uint4(0, 0, 0, 0);
            }
#pragma unroll
            for (int u = 0; u < 4; ++u) {
                floatx2 p;
                p = __builtin_amdgcn_cvt_pk_f32_fp8(g[u].x, false); a[0]  = fmaf(vv[u], p[0], a[0]);  a[1]  = fmaf(vv[u], p[1], a[1]);
                p = __builtin_amdgcn_cvt_pk_f32_fp8(g[u].x, true);  a[2]  = fmaf(vv[u], p[0], a[2]);  a[3]  = fmaf(vv[u], p[1], a[3]);
                p = __builtin_amdgcn_cvt_pk_f32_fp8(g[u].y, false); a[4]  = fmaf(vv[u], p[0], a[4]);  a[5]  = fmaf(vv[u], p[1], a[5]);
                p = __builtin_amdgcn_cvt_pk_f32_fp8(g[u].y, true);  a[6]  = fmaf(vv[u], p[0], a[6]);  a[7]  = fmaf(vv[u], p[1], a[7]);
                p = __builtin_amdgcn_cvt_pk_f32_fp8(g[u].z, false); a[8]  = fmaf(vv[u], p[0], a[8]);  a[9]  = fmaf(vv[u], p[1], a[9]);
                p = __builtin_amdgcn_cvt_pk_f32_fp8(g[u].z, true);  a[10] = fmaf(vv[u], p[0], a[10]); a[11] = fmaf(vv[u], p[1], a[11]);
                p = __builtin_amdgcn_cvt_pk_f32_fp8(g[u].w, false); a[12] = fmaf(vv[u], p[0], a[12]); a[13] = fmaf(vv[u], p[1], a[13]);
                p = __builtin_amdgcn_cvt_pk_f32_fp8(g[u].w, true);  a[14] = fmaf(vv[u], p[0], a[14]); a[15] = fmaf(vv[u], p[1], a[15]);
            }
        }
    }
#pragma unroll
    for (int j = 0; j < 16; ++j) {
        a[j] += __shfl_xor(a[j], 16);
        a[j] += __shfl_xor(a[j], 32);
    }
    if (q == 0) {
        uint4 o;
        o.x = pack4fp8(SP_OUT * a[0],  SP_OUT * a[1],  SP_OUT * a[2],  SP_OUT * a[3]);
        o.y = pack4fp8(SP_OUT * a[4],  SP_OUT * a[5],  SP_OUT * a[6],  SP_OUT * a[7]);
        o.z = pack4fp8(SP_OUT * a[8],  SP_OUT * a[9],  SP_OUT * a[10], SP_OUT * a[11]);
        o.w = pack4fp8(SP_OUT * a[12], SP_OUT * a[13], SP_OUT * a[14], SP_OUT * a[15]);
        *(uint4*)(cout8 + (size_t)r * H_LAT + l16 * 16) = o;
    }
}

// ---------------- fused classifier: Z = ((emb+c1+c2+c3)/4) @ W_cls + b_cls; log_softmax -------
__global__ void __launch_bounds__(256) cls_kernel(const unsigned short* __restrict__ emb,
                                                  const unsigned char* __restrict__ c1,
                                                  const unsigned char* __restrict__ c2,
                                                  const unsigned char* __restrict__ c3,
                                                  const float* __restrict__ W,
                                                  const float* __restrict__ bc,
                                                  float* __restrict__ out) {
    __shared__ float Wl[H_LAT * N_CLASS];
    __shared__ float bl[N_CLASS];
    for (int i = threadIdx.x; i < H_LAT * N_CLASS; i += 256) Wl[i] = W[i];
    if (threadIdx.x < N_CLASS) bl[threadIdx.x] = bc[threadIdx.x];
    __syncthreads();

    int r = blockIdx.x * 256 + threadIdx.x;
    if (r >= N_NODES) return;

    float Z[N_CLASS];
#pragma unroll
    for (int c = 0; c < N_CLASS; ++c) Z[c] = bl[c];

    const unsigned short* p0 = emb + (size_t)r * H_LAT;
    const unsigned char*  p1 = c1 + (size_t)r * H_LAT;
    const unsigned char*  p2 = c2 + (size_t)r * H_LAT;
    const unsigned char*  p3 = c3 + (size_t)r * H_LAT;

    for (int f = 0; f < H_LAT; f += 8) {
        uint4 ge = *(const uint4*)(p0 + f);
        uint2 h1 = *(const uint2*)(p1 + f);
        uint2 h2 = *(const uint2*)(p2 + f);
        uint2 h3 = *(const uint2*)(p3 + f);
        float af[8];
        floatx2 pa, pb, pc;
        pa = __builtin_amdgcn_cvt_pk_f32_fp8(h1.x, false);
        pb = __builtin_amdgcn_cvt_pk_f32_fp8(h2.x, false);
        pc = __builtin_amdgcn_cvt_pk_f32_fp8(h3.x, false);
        af[0] = 0.25f * (blo(ge.x) + pa[0] * INV1 + pb[0] * INV2 + pc[0] * INV3);
        af[1] = 0.25f * (bhi(ge.x) + pa[1] * INV1 + pb[1] * INV2 + pc[1] * INV3);
        pa = __builtin_amdgcn_cvt_pk_f32_fp8(h1.x, true);
        pb = __builtin_amdgcn_cvt_pk_f32_fp8(h2.x, true);
        pc = __builtin_amdgcn_cvt_pk_f32_fp8(h3.x, true);
        af[2] = 0.25f * (blo(ge.y) + pa[0] * INV1 + pb[0] * INV2 + pc[0] * INV3);
        af[3] = 0.25f * (bhi(ge.y) + pa[1] * INV1 + pb[1] * INV2 + pc[1] * INV3);
        pa = __builtin_amdgcn_cvt_pk_f32_fp8(h1.y, false);
        pb = __builtin_amdgcn_cvt_pk_f32_fp8(h2.y, false);
        pc = __builtin_amdgcn_cvt_pk_f32_fp8(h3.y, false);
        af[4] = 0.25f * (blo(ge.z) + pa[0] * INV1 + pb[0] * INV2 + pc[0] * INV3);
        af[5] = 0.25f * (bhi(ge.z) + pa[1] * INV1 + pb[1] * INV2 + pc[1] * INV3);
        pa = __builtin_amdgcn_cvt_pk_f32_fp8(h1.y, true);
        pb = __builtin_amdgcn_cvt_pk_f32_fp8(h2.y, true);
        pc = __builtin_amdgcn_cvt_pk_f32_fp8(h3.y, true);
        af[6] = 0.25f * (blo(ge.w) + pa[0] * INV1 + pb[0] * INV2 + pc[0] * INV3);
        af[7] = 0.25f * (bhi(ge.w) + pa[1] * INV1 + pb[1] * INV2 + pc[1] * INV3);
#pragma unroll
        for (int j = 0; j < 8; ++j) {
            const float* wrow = &Wl[(f + j) * N_CLASS];
#pragma unroll
            for (int c = 0; c < N_CLASS; ++c) Z[c] = fmaf(af[j], wrow[c], Z[c]);
        }
    }

    float m = Z[0];
#pragma unroll
    for (int c = 1; c < N_CLASS; ++c) m = fmaxf(m, Z[c]);
    float s = 0.f;
#pragma unroll
    for (int c = 0; c < N_CLASS; ++c) s += __expf(Z[c] - m);
    float ls = __logf(s) + m;
#pragma unroll
    for (int c = 0; c < N_CLASS; ++c) out[(size_t)r * N_CLASS + c] = Z[c] - ls;
}

// ---------------- launch ----------------
extern "C" void kernel_launch(void* const* d_in, const int* in_sizes, int n_in,
                              void* d_out, int out_size, void* d_ws, size_t ws_size,
                              hipStream_t stream) {
    const float* X        = (const float*)d_in[0];
    const float* W_red    = (const float*)d_in[1];
    const float* b_red    = (const float*)d_in[2];
    const float* W_cls    = (const float*)d_in[3];
    const float* b_cls    = (const float*)d_in[4];
    const float* e_vals   = (const float*)d_in[5];
    const int*   e_rows   = (const int*)d_in[6];
    const int*   e_cols   = (const int*)d_in[7];
    float* out = (float*)d_out;

    char* p = (char*)d_ws;
    auto carve = [&](size_t bytes) -> void* {
        void* r = (void*)p;
        p += (bytes + 255) & ~(size_t)255;
        return r;
    };
    unsigned short* WT   = (unsigned short*)carve((size_t)H_LAT * D_IN * 2);
    unsigned short* emb  = (unsigned short*)carve((size_t)N_TOTAL * H_LAT * 2);
    unsigned char*  emb8 = (unsigned char*)carve((size_t)N_TOTAL * H_LAT);
    unsigned char*  c1_8 = (unsigned char*)carve((size_t)N_TOTAL * H_LAT);
    unsigned char*  c2_8 = (unsigned char*)carve((size_t)N_TOTAL * H_LAT);
    unsigned char*  c3_8 = (unsigned char*)carve((size_t)N_TOTAL * H_LAT);
    int*   row_ptr     = (int*)carve((size_t)CNT_PAD * 4);
    int*   bcnt        = (int*)carve((size_t)NB * 4);
    int*   bptr        = (int*)carve((size_t)(NB + 1) * 4);
    int*   bucket_fill = (int*)carve((size_t)NB * 4);
    int2*  csr_ev      = (int2*)carve((size_t)NNZ_E * 8);
    int2*  binned      = (int2*)c2_8;   // alias: binned dead after binB, before spmm2 writes c2_8

    hipMemsetAsync(bcnt, 0, (size_t)NB * 4, stream);

    prep_wt_kernel<<<512, 256, 0, stream>>>(W_red, WT);
    gemm1_kernel<<<(N_TOTAL + 63) / 64, 256, 0, stream>>>(X, WT, b_red, emb, emb8);

    bcnt_kernel<<<(NNZ_E + CH - 1) / CH, 256, 0, stream>>>(e_rows, bcnt);
    bscan_kernel<<<1, 1024, 0, stream>>>(bcnt, bptr, bucket_fill);
    binA_kernel<<<(NNZ_E + CH - 1) / CH, 256, 0, stream>>>(e_rows, e_cols, e_vals, bucket_fill, binned);
    binB_kernel<<<NB, 256, 0, stream>>>(bptr, binned, row_ptr, csr_ev);

    spmm8_kernel<<<N_TOTAL / 4, 256, 0, stream>>>(emb8, c1_8, row_ptr, csr_ev, N_TOTAL);
    spmm8_kernel<<<N_TOTAL / 4, 256, 0, stream>>>(c1_8, c2_8, row_ptr, csr_ev, N_TOTAL);
    spmm8_kernel<<<N_NODES / 4, 256, 0, stream>>>(c2_8, c3_8, row_ptr, csr_ev, N_NODES);

    cls_kernel<<<(N_NODES + 255) / 256, 256, 0, stream>>>(emb, c1_8, c2_8, c3_8, W_cls, b_cls, out);
}

// Round 2
// 1229.861 us; speedup vs baseline: 1.2639x; 1.0654x over previous
//
#include <hip/hip_runtime.h>

#define N_NODES 100000
#define M_HYPER 50000
#define N_TOTAL 150000
#define D_IN    512
#define H_LAT   256
#define N_CLASS 40
#define NNZ_E   4800000
#define CNT_PAD 151552   // 37 * 4096, >= N_TOTAL+1
#define BK      128
#define BROWS   256
#define NB      ((N_TOTAL + BROWS - 1) / BROWS)   // 586 buckets
#define CH      4096
#define CLS_FB  16       // classifier feature-chunk staged through LDS

// layer scales: emb8 = 16*emb; each spmm stores 8*a (a already carries input scale)
// => c1_8 = 128*c1, c2_8 = 1024*c2, c3_8 = 8192*c3
#define S_EMB   16.0f
#define SP_OUT  8.0f
#define INV1    (1.0f / 128.0f)
#define INV2    (1.0f / 1024.0f)
#define INV3    (1.0f / 8192.0f)

typedef float  floatx4 __attribute__((ext_vector_type(4)));
typedef float  floatx2 __attribute__((ext_vector_type(2)));
typedef __bf16 bf16x8  __attribute__((ext_vector_type(8)));

__device__ __forceinline__ unsigned short bf16_rne(float f) {
    unsigned u = __float_as_uint(f);
    return (unsigned short)((u + 0x7FFFu + ((u >> 16) & 1u)) >> 16);
}
__device__ __forceinline__ float blo(unsigned w) { return __uint_as_float(w << 16); }
__device__ __forceinline__ float bhi(unsigned w) { return __uint_as_float(w & 0xFFFF0000u); }

__device__ __forceinline__ unsigned pack4fp8(float f0, float f1, float f2, float f3) {
    int d = __builtin_amdgcn_cvt_pk_fp8_f32(f0, f1, 0, false);
    d = __builtin_amdgcn_cvt_pk_fp8_f32(f2, f3, d, true);
    return (unsigned)d;
}

// ---------------- W_red transpose + bf16 convert: W[512][256] -> WT[256][512] ----------------
__global__ void __launch_bounds__(256) prep_wt_kernel(const float* __restrict__ W,
                                                      unsigned short* __restrict__ WT) {
    int t = blockIdx.x * 256 + threadIdx.x;
    if (t < D_IN * H_LAT) {
        int k = t >> 8;
        int n = t & 255;
        WT[n * D_IN + k] = bf16_rne(W[t]);
    }
}

// ---------------- GEMM1: emb = X @ W_red + b_red  (LDS-tiled bf16 MFMA) ----------------------
__global__ void __launch_bounds__(256, 3) gemm1_kernel(const float* __restrict__ X,
                                                       const unsigned short* __restrict__ WT,
                                                       const float* __restrict__ brd,
                                                       unsigned short* __restrict__ emb,
                                                       unsigned char* __restrict__ emb8) {
    __shared__ __align__(16) unsigned short smem[64 * (H_LAT + 8)];   // 33.8 KB
    unsigned short (*As)[BK + 8]    = (unsigned short (*)[BK + 8])smem;
    unsigned short (*Cs)[H_LAT + 8] = (unsigned short (*)[H_LAT + 8])smem;

    int tid  = threadIdx.x;
    int wv   = tid >> 6;
    int lane = tid & 63;
    int l16  = lane & 15;
    int quad = lane >> 4;
    int row0 = blockIdx.x * 64;

    int cst = (tid & 31) << 2;   // staging col (float idx), fixed per thread
    int rst = tid >> 5;          // staging row base 0..7
    const float* xbase = X + cst;

    float4 pf[8];
#pragma unroll
    for (int j = 0; j < 8; ++j) {
        int gr = min(row0 + rst + 8 * j, N_TOTAL - 1);
        pf[j] = *(const float4*)(xbase + (size_t)gr * D_IN);
    }

    floatx4 acc[4][4];
#pragma unroll
    for (int a = 0; a < 4; ++a)
#pragma unroll
        for (int b = 0; b < 4; ++b) acc[a][b] = (floatx4)0.f;

#pragma unroll 1
    for (int k0 = 0; k0 < D_IN; k0 += BK) {
        // regs (chunk k0) -> LDS as bf16
#pragma unroll
        for (int j = 0; j < 8; ++j) {
            ushort4 u;
            u.x = bf16_rne(pf[j].x); u.y = bf16_rne(pf[j].y);
            u.z = bf16_rne(pf[j].z); u.w = bf16_rne(pf[j].w);
            *(ushort4*)(&As[rst + 8 * j][cst]) = u;
        }
        __syncthreads();
        // issue next chunk's global loads now; they land during the MFMA phase below
        if (k0 + BK < D_IN) {
#pragma unroll
            for (int j = 0; j < 8; ++j) {
                int gr = min(row0 + rst + 8 * j, N_TOTAL - 1);
                pf[j] = *(const float4*)(xbase + (size_t)gr * D_IN + k0 + BK);
            }
        }
#pragma unroll
        for (int ks = 0; ks < BK; ks += 32) {
            bf16x8 af[4];
#pragma unroll
            for (int rt = 0; rt < 4; ++rt)
                af[rt] = *(const bf16x8*)(&As[rt * 16 + l16][ks + quad * 8]);
#pragma unroll
            for (int ct = 0; ct < 4; ++ct) {
                int col = wv * 64 + ct * 16 + l16;
                bf16x8 bw = *(const bf16x8*)(WT + (size_t)col * D_IN + k0 + ks + quad * 8);
#pragma unroll
                for (int rt = 0; rt < 4; ++rt)
                    acc[rt][ct] = __builtin_amdgcn_mfma_f32_16x16x32_bf16(af[rt], bw, acc[rt][ct], 0, 0, 0);
            }
        }
        __syncthreads();
    }

    // acc (+bias) -> LDS row-major
#pragma unroll
    for (int ct = 0; ct < 4; ++ct) {
        int col = wv * 64 + ct * 16 + l16;
        float bias = brd[col];
#pragma unroll
        for (int rt = 0; rt < 4; ++rt)
#pragma unroll
            for (int r = 0; r < 4; ++r)
                Cs[rt * 16 + quad * 4 + r][col] = bf16_rne(acc[rt][ct][r] + bias);
    }
    __syncthreads();

    // bf16 store, coalesced uint4, only rows < N_NODES
    int nbf = N_NODES - row0;
#pragma unroll
    for (int j = 0; j < 8; ++j) {
        int idx = tid + 256 * j;
        int r = idx >> 5;
        int cq = (idx & 31) * 8;
        if (r < nbf)
            *(uint4*)(emb + (size_t)(row0 + r) * H_LAT + cq) = *(const uint4*)(&Cs[r][cq]);
    }
    // fp8 store, coalesced uint4, all valid rows
#pragma unroll
    for (int j = 0; j < 4; ++j) {
        int idx = tid + 256 * j;
        int r = idx >> 4;
        int cq = (idx & 15) * 16;
        if (row0 + r < N_TOTAL) {
            const unsigned short* s = &Cs[r][cq];
            uint4 w0 = *(const uint4*)s;
            uint4 w1 = *(const uint4*)(s + 8);
            uint4 o;
            o.x = pack4fp8(S_EMB * blo(w0.x), S_EMB * bhi(w0.x), S_EMB * blo(w0.y), S_EMB * bhi(w0.y));
            o.y = pack4fp8(S_EMB * blo(w0.z), S_EMB * bhi(w0.z), S_EMB * blo(w0.w), S_EMB * bhi(w0.w));
            o.z = pack4fp8(S_EMB * blo(w1.x), S_EMB * bhi(w1.x), S_EMB * blo(w1.y), S_EMB * bhi(w1.y));
            o.w = pack4fp8(S_EMB * blo(w1.z), S_EMB * bhi(w1.z), S_EMB * blo(w1.w), S_EMB * bhi(w1.w));
            *(uint4*)(emb8 + (size_t)(row0 + r) * H_LAT + cq) = o;
        }
    }
}

// ---------------- coarse bucket counts (586 bins, LDS-aggregated) ----------------
__global__ void __launch_bounds__(256) bcnt_kernel(const int* __restrict__ rows,
                                                   int* __restrict__ bcnt) {
    __shared__ int h[NB];
    int tid = threadIdx.x;
    for (int i = tid; i < NB; i += 256) h[i] = 0;
    __syncthreads();
    long base = (long)blockIdx.x * (CH / 4);
    const int4* r4 = (const int4*)rows;
#pragma unroll
    for (int j = 0; j < 4; ++j) {
        long e = base + j * 256 + tid;
        if (e < NNZ_E / 4) {
            int4 r = r4[e];
            atomicAdd(&h[r.x >> 8], 1);
            atomicAdd(&h[r.y >> 8], 1);
            atomicAdd(&h[r.z >> 8], 1);
            atomicAdd(&h[r.w >> 8], 1);
        }
    }
    __syncthreads();
    for (int i = tid; i < NB; i += 256) {
        int c = h[i];
        if (c) atomicAdd(&bcnt[i], c);
    }
}

// ---------------- bucket scan: 586 values, one block ----------------
__global__ void __launch_bounds__(1024) bscan_kernel(const int* __restrict__ bcnt,
                                                     int* __restrict__ bptr,
                                                     int* __restrict__ bucket_fill) {
    __shared__ int ws[16];
    int tid = threadIdx.x;
    int lane = tid & 63, wid = tid >> 6;
    int v = (tid < NB) ? bcnt[tid] : 0;
    int s = v;
#pragma unroll
    for (int d = 1; d < 64; d <<= 1) {
        int o = __shfl_up(s, d);
        if (lane >= d) s += o;
    }
    if (lane == 63) ws[wid] = s;
    __syncthreads();
    if (wid == 0) {
        int w = (lane < 16) ? ws[lane] : 0;
#pragma unroll
        for (int d = 1; d < 16; d <<= 1) {
            int o = __shfl_up(w, d);
            if (lane >= d) w += o;
        }
        if (lane < 16) ws[lane] = w;
    }
    __syncthreads();
    int excl = s - v + ((wid > 0) ? ws[wid - 1] : 0);
    if (tid < NB) {
        bptr[tid] = excl;
        bucket_fill[tid] = excl;
    }
    if (tid == 0) bptr[NB] = NNZ_E;
}

// Phase A: bin edges into 586 coarse buckets (contiguous runs per block-bin -> compact writes)
__global__ void __launch_bounds__(256) binA_kernel(const int* __restrict__ rows,
                                                   const int* __restrict__ cols,
                                                   const float* __restrict__ vals,
                                                   int* __restrict__ bucket_fill,
                                                   int2* __restrict__ binned) {
    __shared__ int hist[NB];
    int tid = threadIdx.x;
    long base = (long)blockIdx.x * CH;
    for (int i = tid; i < NB; i += 256) hist[i] = 0;
    __syncthreads();

    int mybkt[16];
    int myrl[16];
#pragma unroll
    for (int j = 0; j < 16; ++j) {
        long e = base + j * 256 + tid;
        int b = -1, rl = 0;
        if (e < NNZ_E) {
            int r = rows[e];
            b = r >> 8;
            rl = r & 255;
            atomicAdd(&hist[b], 1);
        }
        mybkt[j] = b; myrl[j] = rl;
    }
    __syncthreads();
    for (int b = tid; b < NB; b += 256) {
        int c = hist[b];
        int g = 0;
        if (c > 0) g = atomicAdd(&bucket_fill[b], c);
        hist[b] = g;
    }
    __syncthreads();
#pragma unroll
    for (int j = 0; j < 16; ++j) {
        long e = base + j * 256 + tid;
        if (e < NNZ_E) {
            int b = mybkt[j];
            int pos = atomicAdd(&hist[b], 1);
            int c = cols[e];
            float v = vals[e];
            binned[pos] = make_int2(c | (myrl[j] << 18), __float_as_int(v));
        }
    }
}

// Phase B: one bucket per block. LDS 256-bin histogram + LDS scan -> row_ptr + scatter.
__global__ void __launch_bounds__(256) binB_kernel(const int* __restrict__ bptr,
                                                   const int2* __restrict__ binned,
                                                   int* __restrict__ row_ptr,
                                                   int2* __restrict__ csr_ev) {
    __shared__ int lh[256];
    __shared__ int lofs[256];
    __shared__ int wsum[4];
    int b = blockIdx.x;
    int tid = threadIdx.x;
    int s = bptr[b], e = bptr[b + 1];

    lh[tid] = 0;
    __syncthreads();
    for (int t = s + tid; t < e; t += 256)
        atomicAdd(&lh[((unsigned)binned[t].x) >> 18], 1);
    __syncthreads();

    int v = lh[tid];
    int lane = tid & 63, wid = tid >> 6;
    int sc = v;
#pragma unroll
    for (int d = 1; d < 64; d <<= 1) {
        int o = __shfl_up(sc, d);
        if (lane >= d) sc += o;
    }
    if (lane == 63) wsum[wid] = sc;
    __syncthreads();
    int woff = 0;
    if (wid > 0) woff = wsum[0];
    if (wid > 1) woff += wsum[1];
    if (wid > 2) woff += wsum[2];
    int excl = sc - v + woff;
    lofs[tid] = s + excl;
    row_ptr[b * BROWS + tid] = s + excl;
    __syncthreads();

    for (int t = s + tid; t < e; t += 256) {
        int2 w = binned[t];
        int rl  = ((unsigned)w.x) >> 18;
        int col = w.x & 0x3FFFF;
        int p = atomicAdd(&lofs[rl], 1);
        csr_ev[p] = make_int2(col, w.y);
    }
}

// ---------------- SpMM (fp8): cout8[r,:] = SP_OUT * sum_e val[e] * cin8[col[e],:] --------------
__global__ void __launch_bounds__(256) spmm8_kernel(const unsigned char* __restrict__ cin8,
                                                    unsigned char* __restrict__ cout8,
                                                    const int* __restrict__ row_ptr,
                                                    const int2* __restrict__ csr_ev,
                                                    int nrows) {
    int r = (blockIdx.x * 256 + threadIdx.x) >> 6;
    if (r >= nrows) return;
    int lane = threadIdx.x & 63;
    int q   = lane >> 4;
    int l16 = lane & 15;
    int beg = row_ptr[r], end = row_ptr[r + 1];

    float a[16];
#pragma unroll
    for (int j = 0; j < 16; ++j) a[j] = 0.f;
    const unsigned char* basep = cin8 + l16 * 16;

    for (int b = beg; b < end; b += 64) {
        int e = b + lane;
        int2 ev = (e < end) ? csr_ev[e] : make_int2(0, 0);  // col 0 / val 0 -> harmless
        int n = min(64, end - b);
        for (int i = 0; i < n; i += 16) {
            int cc[4]; float vv[4]; uint4 g[4];
#pragma unroll
            for (int u = 0; u < 4; ++u) {
                int src = i + 4 * u + q;
                cc[u] = __shfl(ev.x, src);
                vv[u] = __uint_as_float((unsigned)__shfl(ev.y, src));
            }
#pragma unroll
            for (int u = 0; u < 4; ++u) {
                if (i + 4 * u < n) g[u] = *(const uint4*)(basep + (size_t)cc[u] * H_LAT);
                else               g[u] = make_uint4(0, 0, 0, 0);
            }
#pragma unroll
            for (int u = 0; u < 4; ++u) {
                floatx2 p;
                p = __builtin_amdgcn_cvt_pk_f32_fp8(g[u].x, false); a[0]  = fmaf(vv[u], p[0], a[0]);  a[1]  = fmaf(vv[u], p[1], a[1]);
                p = __builtin_amdgcn_cvt_pk_f32_fp8(g[u].x, true);  a[2]  = fmaf(vv[u], p[0], a[2]);  a[3]  = fmaf(vv[u], p[1], a[3]);
                p = __builtin_amdgcn_cvt_pk_f32_fp8(g[u].y, false); a[4]  = fmaf(vv[u], p[0], a[4]);  a[5]  = fmaf(vv[u], p[1], a[5]);
                p = __builtin_amdgcn_cvt_pk_f32_fp8(g[u].y, true);  a[6]  = fmaf(vv[u], p[0], a[6]);  a[7]  = fmaf(vv[u], p[1], a[7]);
                p = __builtin_amdgcn_cvt_pk_f32_fp8(g[u].z, false); a[8]  = fmaf(vv[u], p[0], a[8]);  a[9]  = fmaf(vv[u], p[1], a[9]);
                p = __builtin_amdgcn_cvt_pk_f32_fp8(g[u].z, true);  a[10] = fmaf(vv[u], p[0], a[10]); a[11] = fmaf(vv[u], p[1], a[11]);
                p = __builtin_amdgcn_cvt_pk_f32_fp8(g[u].w, false); a[12] = fmaf(vv[u], p[0], a[12]); a[13] = fmaf(vv[u], p[1], a[13]);
                p = __builtin_amdgcn_cvt_pk_f32_fp8(g[u].w, true);  a[14] = fmaf(vv[u], p[0], a[14]); a[15] = fmaf(vv[u], p[1], a[15]);
            }
        }
    }
#pragma unroll
    for (int j = 0; j < 16; ++j) {
        a[j] += __shfl_xor(a[j], 16);
        a[j] += __shfl_xor(a[j], 32);
    }
    if (q == 0) {
        uint4 o;
        o.x = pack4fp8(SP_OUT * a[0],  SP_OUT * a[1],  SP_OUT * a[2],  SP_OUT * a[3]);
        o.y = pack4fp8(SP_OUT * a[4],  SP_OUT * a[5],  SP_OUT * a[6],  SP_OUT * a[7]);
        o.z = pack4fp8(SP_OUT * a[8],  SP_OUT * a[9],  SP_OUT * a[10], SP_OUT * a[11]);
        o.w = pack4fp8(SP_OUT * a[12], SP_OUT * a[13], SP_OUT * a[14], SP_OUT * a[15]);
        *(uint4*)(cout8 + (size_t)r * H_LAT + l16 * 16) = o;
    }
}

// ---------------- fused classifier: Z = ((emb+c1+c2+c3)/4) @ W_cls + b_cls; log_softmax -------
// LDS-staged: cooperative coalesced loads of 16-feature chunks (each HBM line consumed once),
// then per-thread row compute from LDS. Fixes the 4.7x HBM over-fetch of the strided version.
__global__ void __launch_bounds__(256, 2) cls_kernel(const unsigned short* __restrict__ emb,
                                                     const unsigned char* __restrict__ c1,
                                                     const unsigned char* __restrict__ c2,
                                                     const unsigned char* __restrict__ c3,
                                                     const float* __restrict__ W,
                                                     const float* __restrict__ bc,
                                                     float* __restrict__ out) {
    __shared__ float Wl[H_LAT * N_CLASS];                       // 40.0 KB
    __shared__ float bl[N_CLASS];
    __shared__ __align__(16) unsigned short embs[256][24];      // 16 used + pad (48B stride)
    __shared__ __align__(16) unsigned char  c1s[256][32];       // 16 used + pad (32B stride)
    __shared__ __align__(16) unsigned char  c2s[256][32];
    __shared__ __align__(16) unsigned char  c3s[256][32];

    int tid = threadIdx.x;
    for (int i = tid; i < H_LAT * N_CLASS; i += 256) Wl[i] = W[i];
    if (tid < N_CLASS) bl[tid] = bc[tid];
    __syncthreads();

    int row0 = blockIdx.x * 256;
    int r = row0 + tid;
    bool active = (r < N_NODES);

    float Z[N_CLASS];
#pragma unroll
    for (int c = 0; c < N_CLASS; ++c) Z[c] = bl[c];

    int erow  = tid >> 1;
    int ehalf = tid & 1;
    int grc = min(r, N_NODES - 1);

#pragma unroll 1
    for (int f0 = 0; f0 < H_LAT; f0 += CLS_FB) {
        // ---- stage chunk (coalesced) ----
#pragma unroll
        for (int j = 0; j < 2; ++j) {
            int rr = erow + 128 * j;
            int gr = min(row0 + rr, N_NODES - 1);
            *(uint4*)(&embs[rr][ehalf * 8]) =
                *(const uint4*)(emb + (size_t)gr * H_LAT + f0 + ehalf * 8);
        }
        {
            uint4 g1 = *(const uint4*)(c1 + (size_t)grc * H_LAT + f0);
            uint4 g2 = *(const uint4*)(c2 + (size_t)grc * H_LAT + f0);
            uint4 g3 = *(const uint4*)(c3 + (size_t)grc * H_LAT + f0);
            *(uint2*)(&c1s[tid][0]) = make_uint2(g1.x, g1.y);
            *(uint2*)(&c1s[tid][8]) = make_uint2(g1.z, g1.w);
            *(uint2*)(&c2s[tid][0]) = make_uint2(g2.x, g2.y);
            *(uint2*)(&c2s[tid][8]) = make_uint2(g2.z, g2.w);
            *(uint2*)(&c3s[tid][0]) = make_uint2(g3.x, g3.y);
            *(uint2*)(&c3s[tid][8]) = make_uint2(g3.z, g3.w);
        }
        __syncthreads();

        // ---- per-thread row compute from LDS (math identical to unstaged version) ----
        if (active) {
#pragma unroll
            for (int fg = 0; fg < CLS_FB; fg += 8) {
                int f = f0 + fg;
                uint4 ge = *(const uint4*)(&embs[tid][fg]);
                uint2 h1 = *(const uint2*)(&c1s[tid][fg]);
                uint2 h2 = *(const uint2*)(&c2s[tid][fg]);
                uint2 h3 = *(const uint2*)(&c3s[tid][fg]);
                float af[8];
                floatx2 pa, pb, pc;
                pa = __builtin_amdgcn_cvt_pk_f32_fp8(h1.x, false);
                pb = __builtin_amdgcn_cvt_pk_f32_fp8(h2.x, false);
                pc = __builtin_amdgcn_cvt_pk_f32_fp8(h3.x, false);
                af[0] = 0.25f * (blo(ge.x) + pa[0] * INV1 + pb[0] * INV2 + pc[0] * INV3);
                af[1] = 0.25f * (bhi(ge.x) + pa[1] * INV1 + pb[1] * INV2 + pc[1] * INV3);
                pa = __builtin_amdgcn_cvt_pk_f32_fp8(h1.x, true);
                pb = __builtin_amdgcn_cvt_pk_f32_fp8(h2.x, true);
                pc = __builtin_amdgcn_cvt_pk_f32_fp8(h3.x, true);
                af[2] = 0.25f * (blo(ge.y) + pa[0] * INV1 + pb[0] * INV2 + pc[0] * INV3);
                af[3] = 0.25f * (bhi(ge.y) + pa[1] * INV1 + pb[1] * INV2 + pc[1] * INV3);
                pa = __builtin_amdgcn_cvt_pk_f32_fp8(h1.y, false);
                pb = __builtin_amdgcn_cvt_pk_f32_fp8(h2.y, false);
                pc = __builtin_amdgcn_cvt_pk_f32_fp8(h3.y, false);
                af[4] = 0.25f * (blo(ge.z) + pa[0] * INV1 + pb[0] * INV2 + pc[0] * INV3);
                af[5] = 0.25f * (bhi(ge.z) + pa[1] * INV1 + pb[1] * INV2 + pc[1] * INV3);
                pa = __builtin_amdgcn_cvt_pk_f32_fp8(h1.y, true);
                pb = __builtin_amdgcn_cvt_pk_f32_fp8(h2.y, true);
                pc = __builtin_amdgcn_cvt_pk_f32_fp8(h3.y, true);
                af[6] = 0.25f * (blo(ge.w) + pa[0] * INV1 + pb[0] * INV2 + pc[0] * INV3);
                af[7] = 0.25f * (bhi(ge.w) + pa[1] * INV1 + pb[1] * INV2 + pc[1] * INV3);
#pragma unroll
                for (int j = 0; j < 8; ++j) {
                    const float* wrow = &Wl[(f + j) * N_CLASS];
#pragma unroll
                    for (int c = 0; c < N_CLASS; ++c) Z[c] = fmaf(af[j], wrow[c], Z[c]);
                }
            }
        }
        __syncthreads();   // protect LDS reuse by next chunk's stage
    }

    if (!active) return;

    float m = Z[0];
#pragma unroll
    for (int c = 1; c < N_CLASS; ++c) m = fmaxf(m, Z[c]);
    float s = 0.f;
#pragma unroll
    for (int c = 0; c < N_CLASS; ++c) s += __expf(Z[c] - m);
    float ls = __logf(s) + m;
#pragma unroll
    for (int c = 0; c < N_CLASS; ++c) out[(size_t)r * N_CLASS + c] = Z[c] - ls;
}

// ---------------- launch ----------------
extern "C" void kernel_launch(void* const* d_in, const int* in_sizes, int n_in,
                              void* d_out, int out_size, void* d_ws, size_t ws_size,
                              hipStream_t stream) {
    const float* X        = (const float*)d_in[0];
    const float* W_red    = (const float*)d_in[1];
    const float* b_red    = (const float*)d_in[2];
    const float* W_cls    = (const float*)d_in[3];
    const float* b_cls    = (const float*)d_in[4];
    const float* e_vals   = (const float*)d_in[5];
    const int*   e_rows   = (const int*)d_in[6];
    const int*   e_cols   = (const int*)d_in[7];
    float* out = (float*)d_out;

    char* p = (char*)d_ws;
    auto carve = [&](size_t bytes) -> void* {
        void* r = (void*)p;
        p += (bytes + 255) & ~(size_t)255;
        return r;
    };
    unsigned short* WT   = (unsigned short*)carve((size_t)H_LAT * D_IN * 2);
    unsigned short* emb  = (unsigned short*)carve((size_t)N_TOTAL * H_LAT * 2);
    unsigned char*  emb8 = (unsigned char*)carve((size_t)N_TOTAL * H_LAT);
    unsigned char*  c1_8 = (unsigned char*)carve((size_t)N_TOTAL * H_LAT);
    unsigned char*  c2_8 = (unsigned char*)carve((size_t)N_TOTAL * H_LAT);
    unsigned char*  c3_8 = (unsigned char*)carve((size_t)N_TOTAL * H_LAT);
    int*   row_ptr     = (int*)carve((size_t)CNT_PAD * 4);
    int*   bcnt        = (int*)carve((size_t)NB * 4);
    int*   bptr        = (int*)carve((size_t)(NB + 1) * 4);
    int*   bucket_fill = (int*)carve((size_t)NB * 4);
    int2*  csr_ev      = (int2*)carve((size_t)NNZ_E * 8);
    int2*  binned      = (int2*)c2_8;   // alias: binned dead after binB, before spmm2 writes c2_8

    hipMemsetAsync(bcnt, 0, (size_t)NB * 4, stream);

    prep_wt_kernel<<<512, 256, 0, stream>>>(W_red, WT);
    gemm1_kernel<<<(N_TOTAL + 63) / 64, 256, 0, stream>>>(X, WT, b_red, emb, emb8);

    bcnt_kernel<<<(NNZ_E + CH - 1) / CH, 256, 0, stream>>>(e_rows, bcnt);
    bscan_kernel<<<1, 1024, 0, stream>>>(bcnt, bptr, bucket_fill);
    binA_kernel<<<(NNZ_E + CH - 1) / CH, 256, 0, stream>>>(e_rows, e_cols, e_vals, bucket_fill, binned);
    binB_kernel<<<NB, 256, 0, stream>>>(bptr, binned, row_ptr, csr_ev);

    spmm8_kernel<<<N_TOTAL / 4, 256, 0, stream>>>(emb8, c1_8, row_ptr, csr_ev, N_TOTAL);
    spmm8_kernel<<<N_TOTAL / 4, 256, 0, stream>>>(c1_8, c2_8, row_ptr, csr_ev, N_TOTAL);
    spmm8_kernel<<<N_NODES / 4, 256, 0, stream>>>(c2_8, c3_8, row_ptr, csr_ev, N_NODES);

    cls_kernel<<<(N_NODES + 255) / 256, 256, 0, stream>>>(emb, c1_8, c2_8, c3_8, W_cls, b_cls, out);
}

// Round 5
// 1209.400 us; speedup vs baseline: 1.2853x; 1.0169x over previous
//
#include <hip/hip_runtime.h>

#define N_NODES 100000
#define M_HYPER 50000
#define N_TOTAL 150000
#define D_IN    512
#define H_LAT   256
#define N_CLASS 40
#define NNZ_E   4800000
#define CNT_PAD 151552   // 37 * 4096, >= N_TOTAL+1
#define BK      128
#define BROWS   256
#define NB      ((N_TOTAL + BROWS - 1) / BROWS)   // 586 buckets
#define CH      4096
#define CLS_FB  16       // classifier feature-chunk staged through LDS

// layer scales: emb8 = 16*emb; each spmm stores 8*a (a already carries input scale)
// => c1_8 = 128*c1, c2_8 = 1024*c2, c3_8 = 8192*c3
#define S_EMB   16.0f
#define SP_OUT  8.0f
#define INV1    (1.0f / 128.0f)
#define INV2    (1.0f / 1024.0f)
#define INV3    (1.0f / 8192.0f)

typedef float  floatx4 __attribute__((ext_vector_type(4)));
typedef float  floatx2 __attribute__((ext_vector_type(2)));
typedef __bf16 bf16x8  __attribute__((ext_vector_type(8)));

__device__ __forceinline__ unsigned short bf16_rne(float f) {
    unsigned u = __float_as_uint(f);
    return (unsigned short)((u + 0x7FFFu + ((u >> 16) & 1u)) >> 16);
}
__device__ __forceinline__ float blo(unsigned w) { return __uint_as_float(w << 16); }
__device__ __forceinline__ float bhi(unsigned w) { return __uint_as_float(w & 0xFFFF0000u); }

__device__ __forceinline__ unsigned pack4fp8(float f0, float f1, float f2, float f3) {
    int d = __builtin_amdgcn_cvt_pk_fp8_f32(f0, f1, 0, false);
    d = __builtin_amdgcn_cvt_pk_fp8_f32(f2, f3, d, true);
    return (unsigned)d;
}

// ---------------- W_red transpose + bf16 convert: W[512][256] -> WT[256][512] ----------------
__global__ void __launch_bounds__(256) prep_wt_kernel(const float* __restrict__ W,
                                                      unsigned short* __restrict__ WT) {
    int t = blockIdx.x * 256 + threadIdx.x;
    if (t < D_IN * H_LAT) {
        int k = t >> 8;
        int n = t & 255;
        WT[n * D_IN + k] = bf16_rne(W[t]);
    }
}

// ---------------- GEMM1: emb = X @ W_red + b_red  (LDS-tiled bf16 MFMA) ----------------------
// vmcnt-FIFO fix: all B-fragment (bw) global loads for a chunk are issued BEFORE the next
// A-chunk's HBM prefetch (pf). vmcnt retires in issue order, so if bw were issued after pf,
// every bw consume inside the MFMA loop had to drain the ~900-cyc HBM prefetch first
// (-> MfmaUtil 8%). With bw oldest, MFMA waits only on L2-fast bw; pf (youngest) drains at
// the chunk-end ds_write, mostly covered by the MFMA phase. Ordering enforced with plain
// asm memory fences (no instruction emitted).
__global__ void __launch_bounds__(256, 2) gemm1_kernel(const float* __restrict__ X,
                                                       const unsigned short* __restrict__ WT,
                                                       const float* __restrict__ brd,
                                                       unsigned short* __restrict__ emb,
                                                       unsigned char* __restrict__ emb8) {
    __shared__ __align__(16) unsigned short smem[64 * (H_LAT + 8)];   // 33.8 KB
    unsigned short (*As)[BK + 8]    = (unsigned short (*)[BK + 8])smem;
    unsigned short (*Cs)[H_LAT + 8] = (unsigned short (*)[H_LAT + 8])smem;

    int tid  = threadIdx.x;
    int wv   = tid >> 6;
    int lane = tid & 63;
    int l16  = lane & 15;
    int quad = lane >> 4;
    int row0 = blockIdx.x * 64;

    int cst = (tid & 31) << 2;   // staging col (float idx), fixed per thread
    int rst = tid >> 5;          // staging row base 0..7
    const float* xbase = X + cst;

    float4 pf[8];
#pragma unroll
    for (int j = 0; j < 8; ++j) {
        int gr = min(row0 + rst + 8 * j, N_TOTAL - 1);
        pf[j] = *(const float4*)(xbase + (size_t)gr * D_IN);
    }

    floatx4 acc[4][4];
#pragma unroll
    for (int a = 0; a < 4; ++a)
#pragma unroll
        for (int b = 0; b < 4; ++b) acc[a][b] = (floatx4)0.f;

#pragma unroll 1
    for (int k0 = 0; k0 < D_IN; k0 += BK) {
        // regs (chunk k0) -> LDS as bf16 (waits vmcnt(0) on pf; pf is the only outstanding)
#pragma unroll
        for (int j = 0; j < 8; ++j) {
            ushort4 u;
            u.x = bf16_rne(pf[j].x); u.y = bf16_rne(pf[j].y);
            u.z = bf16_rne(pf[j].z); u.w = bf16_rne(pf[j].w);
            *(ushort4*)(&As[rst + 8 * j][cst]) = u;
        }
        __syncthreads();

        // (1) hoist ALL bw loads for this chunk (L2-resident WT) -- issued BEFORE pf
        bf16x8 bw[4][4];
#pragma unroll
        for (int s = 0; s < 4; ++s)
#pragma unroll
            for (int ct = 0; ct < 4; ++ct) {
                int col = wv * 64 + ct * 16 + l16;
                bw[s][ct] = *(const bf16x8*)(WT + (size_t)col * D_IN + k0 + s * 32 + quad * 8);
            }
        asm volatile("" ::: "memory");   // keep bw loads ahead of pf in issue order

        // (2) issue next chunk's HBM prefetch (youngest -> never blocks bw consumption)
        if (k0 + BK < D_IN) {
#pragma unroll
            for (int j = 0; j < 8; ++j) {
                int gr = min(row0 + rst + 8 * j, N_TOTAL - 1);
                pf[j] = *(const float4*)(xbase + (size_t)gr * D_IN + k0 + BK);
            }
        }
        asm volatile("" ::: "memory");   // keep pf issue ahead of the MFMA/LDS phase

        // (3) MFMA phase: LDS af reads + bw regs only (no global loads here)
#pragma unroll
        for (int s = 0; s < 4; ++s) {
            int ks = s * 32;
            bf16x8 af[4];
#pragma unroll
            for (int rt = 0; rt < 4; ++rt)
                af[rt] = *(const bf16x8*)(&As[rt * 16 + l16][ks + quad * 8]);
#pragma unroll
            for (int ct = 0; ct < 4; ++ct) {
#pragma unroll
                for (int rt = 0; rt < 4; ++rt)
                    acc[rt][ct] = __builtin_amdgcn_mfma_f32_16x16x32_bf16(af[rt], bw[s][ct], acc[rt][ct], 0, 0, 0);
            }
        }
        __syncthreads();
    }

    // acc (+bias) -> LDS row-major
#pragma unroll
    for (int ct = 0; ct < 4; ++ct) {
        int col = wv * 64 + ct * 16 + l16;
        float bias = brd[col];
#pragma unroll
        for (int rt = 0; rt < 4; ++rt)
#pragma unroll
            for (int r = 0; r < 4; ++r)
                Cs[rt * 16 + quad * 4 + r][col] = bf16_rne(acc[rt][ct][r] + bias);
    }
    __syncthreads();

    // bf16 store, coalesced uint4, only rows < N_NODES
    int nbf = N_NODES - row0;
#pragma unroll
    for (int j = 0; j < 8; ++j) {
        int idx = tid + 256 * j;
        int r = idx >> 5;
        int cq = (idx & 31) * 8;
        if (r < nbf)
            *(uint4*)(emb + (size_t)(row0 + r) * H_LAT + cq) = *(const uint4*)(&Cs[r][cq]);
    }
    // fp8 store, coalesced uint4, all valid rows
#pragma unroll
    for (int j = 0; j < 4; ++j) {
        int idx = tid + 256 * j;
        int r = idx >> 4;
        int cq = (idx & 15) * 16;
        if (row0 + r < N_TOTAL) {
            const unsigned short* s = &Cs[r][cq];
            uint4 w0 = *(const uint4*)s;
            uint4 w1 = *(const uint4*)(s + 8);
            uint4 o;
            o.x = pack4fp8(S_EMB * blo(w0.x), S_EMB * bhi(w0.x), S_EMB * blo(w0.y), S_EMB * bhi(w0.y));
            o.y = pack4fp8(S_EMB * blo(w0.z), S_EMB * bhi(w0.z), S_EMB * blo(w0.w), S_EMB * bhi(w0.w));
            o.z = pack4fp8(S_EMB * blo(w1.x), S_EMB * bhi(w1.x), S_EMB * blo(w1.y), S_EMB * bhi(w1.y));
            o.w = pack4fp8(S_EMB * blo(w1.z), S_EMB * bhi(w1.z), S_EMB * blo(w1.w), S_EMB * bhi(w1.w));
            *(uint4*)(emb8 + (size_t)(row0 + r) * H_LAT + cq) = o;
        }
    }
}

// ---------------- coarse bucket counts (586 bins, LDS-aggregated) ----------------
__global__ void __launch_bounds__(256) bcnt_kernel(const int* __restrict__ rows,
                                                   int* __restrict__ bcnt) {
    __shared__ int h[NB];
    int tid = threadIdx.x;
    for (int i = tid; i < NB; i += 256) h[i] = 0;
    __syncthreads();
    long base = (long)blockIdx.x * (CH / 4);
    const int4* r4 = (const int4*)rows;
#pragma unroll
    for (int j = 0; j < 4; ++j) {
        long e = base + j * 256 + tid;
        if (e < NNZ_E / 4) {
            int4 r = r4[e];
            atomicAdd(&h[r.x >> 8], 1);
            atomicAdd(&h[r.y >> 8], 1);
            atomicAdd(&h[r.z >> 8], 1);
            atomicAdd(&h[r.w >> 8], 1);
        }
    }
    __syncthreads();
    for (int i = tid; i < NB; i += 256) {
        int c = h[i];
        if (c) atomicAdd(&bcnt[i], c);
    }
}

// ---------------- bucket scan: 586 values, one block ----------------
__global__ void __launch_bounds__(1024) bscan_kernel(const int* __restrict__ bcnt,
                                                     int* __restrict__ bptr,
                                                     int* __restrict__ bucket_fill) {
    __shared__ int ws[16];
    int tid = threadIdx.x;
    int lane = tid & 63, wid = tid >> 6;
    int v = (tid < NB) ? bcnt[tid] : 0;
    int s = v;
#pragma unroll
    for (int d = 1; d < 64; d <<= 1) {
        int o = __shfl_up(s, d);
        if (lane >= d) s += o;
    }
    if (lane == 63) ws[wid] = s;
    __syncthreads();
    if (wid == 0) {
        int w = (lane < 16) ? ws[lane] : 0;
#pragma unroll
        for (int d = 1; d < 16; d <<= 1) {
            int o = __shfl_up(w, d);
            if (lane >= d) w += o;
        }
        if (lane < 16) ws[lane] = w;
    }
    __syncthreads();
    int excl = s - v + ((wid > 0) ? ws[wid - 1] : 0);
    if (tid < NB) {
        bptr[tid] = excl;
        bucket_fill[tid] = excl;
    }
    if (tid == 0) bptr[NB] = NNZ_E;
}

// Phase A: bin edges into 586 coarse buckets (contiguous runs per block-bin -> compact writes)
__global__ void __launch_bounds__(256) binA_kernel(const int* __restrict__ rows,
                                                   const int* __restrict__ cols,
                                                   const float* __restrict__ vals,
                                                   int* __restrict__ bucket_fill,
                                                   int2* __restrict__ binned) {
    __shared__ int hist[NB];
    int tid = threadIdx.x;
    long base = (long)blockIdx.x * CH;
    for (int i = tid; i < NB; i += 256) hist[i] = 0;
    __syncthreads();

    int mybkt[16];
    int myrl[16];
#pragma unroll
    for (int j = 0; j < 16; ++j) {
        long e = base + j * 256 + tid;
        int b = -1, rl = 0;
        if (e < NNZ_E) {
            int r = rows[e];
            b = r >> 8;
            rl = r & 255;
            atomicAdd(&hist[b], 1);
        }
        mybkt[j] = b; myrl[j] = rl;
    }
    __syncthreads();
    for (int b = tid; b < NB; b += 256) {
        int c = hist[b];
        int g = 0;
        if (c > 0) g = atomicAdd(&bucket_fill[b], c);
        hist[b] = g;
    }
    __syncthreads();
#pragma unroll
    for (int j = 0; j < 16; ++j) {
        long e = base + j * 256 + tid;
        if (e < NNZ_E) {
            int b = mybkt[j];
            int pos = atomicAdd(&hist[b], 1);
            int c = cols[e];
            float v = vals[e];
            binned[pos] = make_int2(c | (myrl[j] << 18), __float_as_int(v));
        }
    }
}

// Phase B: one bucket per block. LDS 256-bin histogram + LDS scan -> row_ptr + scatter.
__global__ void __launch_bounds__(256) binB_kernel(const int* __restrict__ bptr,
                                                   const int2* __restrict__ binned,
                                                   int* __restrict__ row_ptr,
                                                   int2* __restrict__ csr_ev) {
    __shared__ int lh[256];
    __shared__ int lofs[256];
    __shared__ int wsum[4];
    int b = blockIdx.x;
    int tid = threadIdx.x;
    int s = bptr[b], e = bptr[b + 1];

    lh[tid] = 0;
    __syncthreads();
    for (int t = s + tid; t < e; t += 256)
        atomicAdd(&lh[((unsigned)binned[t].x) >> 18], 1);
    __syncthreads();

    int v = lh[tid];
    int lane = tid & 63, wid = tid >> 6;
    int sc = v;
#pragma unroll
    for (int d = 1; d < 64; d <<= 1) {
        int o = __shfl_up(sc, d);
        if (lane >= d) sc += o;
    }
    if (lane == 63) wsum[wid] = sc;
    __syncthreads();
    int woff = 0;
    if (wid > 0) woff = wsum[0];
    if (wid > 1) woff += wsum[1];
    if (wid > 2) woff += wsum[2];
    int excl = sc - v + woff;
    lofs[tid] = s + excl;
    row_ptr[b * BROWS + tid] = s + excl;
    __syncthreads();

    for (int t = s + tid; t < e; t += 256) {
        int2 w = binned[t];
        int rl  = ((unsigned)w.x) >> 18;
        int col = w.x & 0x3FFFF;
        int p = atomicAdd(&lofs[rl], 1);
        csr_ev[p] = make_int2(col, w.y);
    }
}

// ---------------- SpMM (fp8): cout8[r,:] = SP_OUT * sum_e val[e] * cin8[col[e],:] --------------
__global__ void __launch_bounds__(256) spmm8_kernel(const unsigned char* __restrict__ cin8,
                                                    unsigned char* __restrict__ cout8,
                                                    const int* __restrict__ row_ptr,
                                                    const int2* __restrict__ csr_ev,
                                                    int nrows) {
    int r = (blockIdx.x * 256 + threadIdx.x) >> 6;
    if (r >= nrows) return;
    int lane = threadIdx.x & 63;
    int q   = lane >> 4;
    int l16 = lane & 15;
    int beg = row_ptr[r], end = row_ptr[r + 1];

    float a[16];
#pragma unroll
    for (int j = 0; j < 16; ++j) a[j] = 0.f;
    const unsigned char* basep = cin8 + l16 * 16;

    for (int b = beg; b < end; b += 64) {
        int e = b + lane;
        int2 ev = (e < end) ? csr_ev[e] : make_int2(0, 0);  // col 0 / val 0 -> harmless
        int n = min(64, end - b);
        for (int i = 0; i < n; i += 16) {
            int cc[4]; float vv[4]; uint4 g[4];
#pragma unroll
            for (int u = 0; u < 4; ++u) {
                int src = i + 4 * u + q;
                cc[u] = __shfl(ev.x, src);
                vv[u] = __uint_as_float((unsigned)__shfl(ev.y, src));
            }
#pragma unroll
            for (int u = 0; u < 4; ++u) {
                if (i + 4 * u < n) g[u] = *(const uint4*)(basep + (size_t)cc[u] * H_LAT);
                else               g[u] = make_uint4(0, 0, 0, 0);
            }
#pragma unroll
            for (int u = 0; u < 4; ++u) {
                floatx2 p;
                p = __builtin_amdgcn_cvt_pk_f32_fp8(g[u].x, false); a[0]  = fmaf(vv[u], p[0], a[0]);  a[1]  = fmaf(vv[u], p[1], a[1]);
                p = __builtin_amdgcn_cvt_pk_f32_fp8(g[u].x, true);  a[2]  = fmaf(vv[u], p[0], a[2]);  a[3]  = fmaf(vv[u], p[1], a[3]);
                p = __builtin_amdgcn_cvt_pk_f32_fp8(g[u].y, false); a[4]  = fmaf(vv[u], p[0], a[4]);  a[5]  = fmaf(vv[u], p[1], a[5]);
                p = __builtin_amdgcn_cvt_pk_f32_fp8(g[u].y, true);  a[6]  = fmaf(vv[u], p[0], a[6]);  a[7]  = fmaf(vv[u], p[1], a[7]);
                p = __builtin_amdgcn_cvt_pk_f32_fp8(g[u].z, false); a[8]  = fmaf(vv[u], p[0], a[8]);  a[9]  = fmaf(vv[u], p[1], a[9]);
                p = __builtin_amdgcn_cvt_pk_f32_fp8(g[u].z, true);  a[10] = fmaf(vv[u], p[0], a[10]); a[11] = fmaf(vv[u], p[1], a[11]);
                p = __builtin_amdgcn_cvt_pk_f32_fp8(g[u].w, false); a[12] = fmaf(vv[u], p[0], a[12]); a[13] = fmaf(vv[u], p[1], a[13]);
                p = __builtin_amdgcn_cvt_pk_f32_fp8(g[u].w, true);  a[14] = fmaf(vv[u], p[0], a[14]); a[15] = fmaf(vv[u], p[1], a[15]);
            }
        }
    }
#pragma unroll
    for (int j = 0; j < 16; ++j) {
        a[j] += __shfl_xor(a[j], 16);
        a[j] += __shfl_xor(a[j], 32);
    }
    if (q == 0) {
        uint4 o;
        o.x = pack4fp8(SP_OUT * a[0],  SP_OUT * a[1],  SP_OUT * a[2],  SP_OUT * a[3]);
        o.y = pack4fp8(SP_OUT * a[4],  SP_OUT * a[5],  SP_OUT * a[6],  SP_OUT * a[7]);
        o.z = pack4fp8(SP_OUT * a[8],  SP_OUT * a[9],  SP_OUT * a[10], SP_OUT * a[11]);
        o.w = pack4fp8(SP_OUT * a[12], SP_OUT * a[13], SP_OUT * a[14], SP_OUT * a[15]);
        *(uint4*)(cout8 + (size_t)r * H_LAT + l16 * 16) = o;
    }
}

// ---------------- fused classifier: Z = ((emb+c1+c2+c3)/4) @ W_cls + b_cls; log_softmax -------
__global__ void __launch_bounds__(256, 2) cls_kernel(const unsigned short* __restrict__ emb,
                                                     const unsigned char* __restrict__ c1,
                                                     const unsigned char* __restrict__ c2,
                                                     const unsigned char* __restrict__ c3,
                                                     const float* __restrict__ W,
                                                     const float* __restrict__ bc,
                                                     float* __restrict__ out) {
    __shared__ float Wl[H_LAT * N_CLASS];                       // 40.0 KB
    __shared__ float bl[N_CLASS];
    __shared__ __align__(16) unsigned short embs[256][24];      // 16 used + pad (48B stride)
    __shared__ __align__(16) unsigned char  c1s[256][32];       // 16 used + pad (32B stride)
    __shared__ __align__(16) unsigned char  c2s[256][32];
    __shared__ __align__(16) unsigned char  c3s[256][32];

    int tid = threadIdx.x;
    for (int i = tid; i < H_LAT * N_CLASS; i += 256) Wl[i] = W[i];
    if (tid < N_CLASS) bl[tid] = bc[tid];
    __syncthreads();

    int row0 = blockIdx.x * 256;
    int r = row0 + tid;
    bool active = (r < N_NODES);

    float Z[N_CLASS];
#pragma unroll
    for (int c = 0; c < N_CLASS; ++c) Z[c] = bl[c];

    int erow  = tid >> 1;
    int ehalf = tid & 1;
    int grc = min(r, N_NODES - 1);

#pragma unroll 1
    for (int f0 = 0; f0 < H_LAT; f0 += CLS_FB) {
        // ---- stage chunk (coalesced) ----
#pragma unroll
        for (int j = 0; j < 2; ++j) {
            int rr = erow + 128 * j;
            int gr = min(row0 + rr, N_NODES - 1);
            *(uint4*)(&embs[rr][ehalf * 8]) =
                *(const uint4*)(emb + (size_t)gr * H_LAT + f0 + ehalf * 8);
        }
        {
            uint4 g1 = *(const uint4*)(c1 + (size_t)grc * H_LAT + f0);
            uint4 g2 = *(const uint4*)(c2 + (size_t)grc * H_LAT + f0);
            uint4 g3 = *(const uint4*)(c3 + (size_t)grc * H_LAT + f0);
            *(uint2*)(&c1s[tid][0]) = make_uint2(g1.x, g1.y);
            *(uint2*)(&c1s[tid][8]) = make_uint2(g1.z, g1.w);
            *(uint2*)(&c2s[tid][0]) = make_uint2(g2.x, g2.y);
            *(uint2*)(&c2s[tid][8]) = make_uint2(g2.z, g2.w);
            *(uint2*)(&c3s[tid][0]) = make_uint2(g3.x, g3.y);
            *(uint2*)(&c3s[tid][8]) = make_uint2(g3.z, g3.w);
        }
        __syncthreads();

        // ---- per-thread row compute from LDS (math identical to unstaged version) ----
        if (active) {
#pragma unroll
            for (int fg = 0; fg < CLS_FB; fg += 8) {
                int f = f0 + fg;
                uint4 ge = *(const uint4*)(&embs[tid][fg]);
                uint2 h1 = *(const uint2*)(&c1s[tid][fg]);
                uint2 h2 = *(const uint2*)(&c2s[tid][fg]);
                uint2 h3 = *(const uint2*)(&c3s[tid][fg]);
                float af[8];
                floatx2 pa, pb, pc;
                pa = __builtin_amdgcn_cvt_pk_f32_fp8(h1.x, false);
                pb = __builtin_amdgcn_cvt_pk_f32_fp8(h2.x, false);
                pc = __builtin_amdgcn_cvt_pk_f32_fp8(h3.x, false);
                af[0] = 0.25f * (blo(ge.x) + pa[0] * INV1 + pb[0] * INV2 + pc[0] * INV3);
                af[1] = 0.25f * (bhi(ge.x) + pa[1] * INV1 + pb[1] * INV2 + pc[1] * INV3);
                pa = __builtin_amdgcn_cvt_pk_f32_fp8(h1.x, true);
                pb = __builtin_amdgcn_cvt_pk_f32_fp8(h2.x, true);
                pc = __builtin_amdgcn_cvt_pk_f32_fp8(h3.x, true);
                af[2] = 0.25f * (blo(ge.y) + pa[0] * INV1 + pb[0] * INV2 + pc[0] * INV3);
                af[3] = 0.25f * (bhi(ge.y) + pa[1] * INV1 + pb[1] * INV2 + pc[1] * INV3);
                pa = __builtin_amdgcn_cvt_pk_f32_fp8(h1.y, false);
                pb = __builtin_amdgcn_cvt_pk_f32_fp8(h2.y, false);
                pc = __builtin_amdgcn_cvt_pk_f32_fp8(h3.y, false);
                af[4] = 0.25f * (blo(ge.z) + pa[0] * INV1 + pb[0] * INV2 + pc[0] * INV3);
                af[5] = 0.25f * (bhi(ge.z) + pa[1] * INV1 + pb[1] * INV2 + pc[1] * INV3);
                pa = __builtin_amdgcn_cvt_pk_f32_fp8(h1.y, true);
                pb = __builtin_amdgcn_cvt_pk_f32_fp8(h2.y, true);
                pc = __builtin_amdgcn_cvt_pk_f32_fp8(h3.y, true);
                af[6] = 0.25f * (blo(ge.w) + pa[0] * INV1 + pb[0] * INV2 + pc[0] * INV3);
                af[7] = 0.25f * (bhi(ge.w) + pa[1] * INV1 + pb[1] * INV2 + pc[1] * INV3);
#pragma unroll
                for (int j = 0; j < 8; ++j) {
                    const float* wrow = &Wl[(f + j) * N_CLASS];
#pragma unroll
                    for (int c = 0; c < N_CLASS; ++c) Z[c] = fmaf(af[j], wrow[c], Z[c]);
                }
            }
        }
        __syncthreads();   // protect LDS reuse by next chunk's stage
    }

    if (!active) return;

    float m = Z[0];
#pragma unroll
    for (int c = 1; c < N_CLASS; ++c) m = fmaxf(m, Z[c]);
    float s = 0.f;
#pragma unroll
    for (int c = 0; c < N_CLASS; ++c) s += __expf(Z[c] - m);
    float ls = __logf(s) + m;
#pragma unroll
    for (int c = 0; c < N_CLASS; ++c) out[(size_t)r * N_CLASS + c] = Z[c] - ls;
}

// ---------------- launch ----------------
extern "C" void kernel_launch(void* const* d_in, const int* in_sizes, int n_in,
                              void* d_out, int out_size, void* d_ws, size_t ws_size,
                              hipStream_t stream) {
    const float* X        = (const float*)d_in[0];
    const float* W_red    = (const float*)d_in[1];
    const float* b_red    = (const float*)d_in[2];
    const float* W_cls    = (const float*)d_in[3];
    const float* b_cls    = (const float*)d_in[4];
    const float* e_vals   = (const float*)d_in[5];
    const int*   e_rows   = (const int*)d_in[6];
    const int*   e_cols   = (const int*)d_in[7];
    float* out = (float*)d_out;

    char* p = (char*)d_ws;
    auto carve = [&](size_t bytes) -> void* {
        void* r = (void*)p;
        p += (bytes + 255) & ~(size_t)255;
        return r;
    };
    unsigned short* WT   = (unsigned short*)carve((size_t)H_LAT * D_IN * 2);
    unsigned short* emb  = (unsigned short*)carve((size_t)N_TOTAL * H_LAT * 2);
    unsigned char*  emb8 = (unsigned char*)carve((size_t)N_TOTAL * H_LAT);
    unsigned char*  c1_8 = (unsigned char*)carve((size_t)N_TOTAL * H_LAT);
    unsigned char*  c2_8 = (unsigned char*)carve((size_t)N_TOTAL * H_LAT);
    unsigned char*  c3_8 = (unsigned char*)carve((size_t)N_TOTAL * H_LAT);
    int*   row_ptr     = (int*)carve((size_t)CNT_PAD * 4);
    int*   bcnt        = (int*)carve((size_t)NB * 4);
    int*   bptr        = (int*)carve((size_t)(NB + 1) * 4);
    int*   bucket_fill = (int*)carve((size_t)NB * 4);
    int2*  csr_ev      = (int2*)carve((size_t)NNZ_E * 8);
    int2*  binned      = (int2*)c2_8;   // alias: binned dead after binB, before spmm2 writes c2_8

    hipMemsetAsync(bcnt, 0, (size_t)NB * 4, stream);

    prep_wt_kernel<<<512, 256, 0, stream>>>(W_red, WT);
    gemm1_kernel<<<(N_TOTAL + 63) / 64, 256, 0, stream>>>(X, WT, b_red, emb, emb8);

    bcnt_kernel<<<(NNZ_E + CH - 1) / CH, 256, 0, stream>>>(e_rows, bcnt);
    bscan_kernel<<<1, 1024, 0, stream>>>(bcnt, bptr, bucket_fill);
    binA_kernel<<<(NNZ_E + CH - 1) / CH, 256, 0, stream>>>(e_rows, e_cols, e_vals, bucket_fill, binned);
    binB_kernel<<<NB, 256, 0, stream>>>(bptr, binned, row_ptr, csr_ev);

    spmm8_kernel<<<N_TOTAL / 4, 256, 0, stream>>>(emb8, c1_8, row_ptr, csr_ev, N_TOTAL);
    spmm8_kernel<<<N_TOTAL / 4, 256, 0, stream>>>(c1_8, c2_8, row_ptr, csr_ev, N_TOTAL);
    spmm8_kernel<<<N_NODES / 4, 256, 0, stream>>>(c2_8, c3_8, row_ptr, csr_ev, N_NODES);

    cls_kernel<<<(N_NODES + 255) / 256, 256, 0, stream>>>(emb, c1_8, c2_8, c3_8, W_cls, b_cls, out);
}